// Round 1
// baseline (615.811 us; speedup 1.0000x reference)
//
#include <hip/hip_runtime.h>

// ConvNN: out[b,g,j] = W1[g]·leaky(W0[g]·x[b] + b0[g]) + b1[g]
// B=1024, SIZE=2048, IN_DIM=D1=D2=64, neg_slope=0.2
//
// Round-3 structure: block = 8 waves x 8 consecutive groups (wave w owns
// group gs*8+w), 512 batches per block. All verified inner math (weight
// fragments, hs transpose, pk_rne, MFMA pairing) is unchanged from round 2.
// Change: layer-1 results are deposited into a 64 KB f32 LDS slab and then
// cooperatively streamed to global as 2 KB-contiguous-per-row dwordx4
// bursts, replacing the 256 B-burst 512KiB-strided float2 stores that were
// collapsing write BW. launch_bounds(512,2) lifts the VGPR cap to 256
// (no spill risk; old (256,3) capped at ~168 with ~190 live).
#define BATCH 1024
#define NGRP  2048
#define DIM   64
#define NEG   0.2f
#define OUTSTRIDE ((size_t)NGRP * DIM)   // 131072 floats between batch rows

#define G_PER_BLK 8
#define B_PER_BLK 512
#define ITERS     (B_PER_BLK / 32)       // 16

typedef __attribute__((ext_vector_type(8)))  short bf16x8;
typedef __attribute__((ext_vector_type(4)))  short short4v;
typedef __attribute__((ext_vector_type(16))) float f32x16;

union frag_u { bf16x8 v; unsigned u[4]; short4v h[2]; };

// pack two f32 -> two bf16 (RNE) in one u32 via v_perm
__device__ __forceinline__ unsigned pk_rne(float a, float b) {
    unsigned ua = __float_as_uint(a), ub = __float_as_uint(b);
    ua += 0x7fffu + ((ua >> 16) & 1u);
    ub += 0x7fffu + ((ub >> 16) & 1u);
    // result: low16 = bf16(a), high16 = bf16(b)
    return __builtin_amdgcn_perm(ub, ua, 0x07060302);
}

// ---- pre-kernel: x f32[1024][64] -> bf16[1024][64] in workspace ----
__global__ void cvt_x_kernel(const float4* __restrict__ x, uint2* __restrict__ xb) {
    int i = blockIdx.x * blockDim.x + threadIdx.x;   // 16384 threads, 1 float4 each
    float4 v = x[i];
    uint2 o;
    o.x = pk_rne(v.x, v.y);
    o.y = pk_rne(v.z, v.w);
    xb[i] = o;
}

__global__ __launch_bounds__(512, 2)
void convnn_kernel(const unsigned short* __restrict__ xb,  // bf16 [1024][64]
                   const float* __restrict__ W0, const float* __restrict__ b0,
                   const float* __restrict__ W1, const float* __restrict__ b1,
                   float* __restrict__ out) {
    // per-wave hidden slab: 32 rows x 64 cols bf16, +4 shorts pad (2-way max, free)
    __shared__ short hs[8][32][68];                  // 34,816 B
    // f32 output exchange slab: 32 batch rows x (8 groups x 64 cols)
    __shared__ float sl[32][G_PER_BLK * DIM];        // 65,536 B  (total ~98 KiB -> 1 blk/CU)

    const int bx   = blockIdx.x;
    const int gs   = bx & 255;              // group-set (8 groups)
    const int bh   = bx >> 8;               // batch half (0/1); bx and bx+256 share weights+XCD
    const int tid  = threadIdx.x;
    const int lane = tid & 63;
    const int wave = tid >> 6;              // 0..7
    const int n    = lane & 31;             // fragment row/col index
    const int koff = (lane >> 5) * 8;       // k sub-chunk per half-wave
    const int g    = gs * G_PER_BLK + wave; // this wave's group

    // ---- load weight B-fragments once (f32 global -> bf16 regs, RNE) ----
    // paired-column assignment: lane n covers weight rows 2n (even acc) and
    // 2n+1 (odd acc), so accE/accO hold adjacent output columns.
    frag_u w0f[4][2], w1f[4][2];
    {
        const float* w0p = W0 + (size_t)g * DIM * DIM;
        const float* w1p = W1 + (size_t)g * DIM * DIM;
        #pragma unroll
        for (int kk = 0; kk < 4; ++kk) {
            #pragma unroll
            for (int p = 0; p < 2; ++p) {
                const float* r0 = w0p + (size_t)(2 * n + p) * DIM + kk * 16 + koff;
                float4 lo = *(const float4*)r0;
                float4 hi = *(const float4*)(r0 + 4);
                w0f[kk][p].u[0] = pk_rne(lo.x, lo.y);
                w0f[kk][p].u[1] = pk_rne(lo.z, lo.w);
                w0f[kk][p].u[2] = pk_rne(hi.x, hi.y);
                w0f[kk][p].u[3] = pk_rne(hi.z, hi.w);
                const float* r1 = w1p + (size_t)(2 * n + p) * DIM + kk * 16 + koff;
                float4 lo1 = *(const float4*)r1;
                float4 hi1 = *(const float4*)(r1 + 4);
                w1f[kk][p].u[0] = pk_rne(lo1.x, lo1.y);
                w1f[kk][p].u[1] = pk_rne(lo1.z, lo1.w);
                w1f[kk][p].u[2] = pk_rne(hi1.x, hi1.y);
                w1f[kk][p].u[3] = pk_rne(hi1.z, hi1.w);
            }
        }
    }
    const float2 b0v = *(const float2*)(b0 + (size_t)g * DIM + 2 * n);
    const float2 b1v = *(const float2*)(b1 + (size_t)g * DIM + 2 * n);

    short (*h)[68] = hs[wave];
    const int tb0 = bh * B_PER_BLK;

    // prefetch tile 0 A-frags (bf16 direct from global, 16B each)
    bf16x8 a[4];
    {
        const unsigned short* xr = xb + (size_t)(tb0 + n) * DIM + koff;
        #pragma unroll
        for (int kk = 0; kk < 4; ++kk) a[kk] = *(const bf16x8*)(xr + kk * 16);
    }

    for (int i = 0; i < ITERS; ++i) {
        const int tb = tb0 + i * 32;        // this iter's 32 batch rows (all waves)
        // prefetch next tile
        bf16x8 an[4];
        {
            int tn = tb0 + (i < ITERS - 1 ? i + 1 : i) * 32;
            const unsigned short* xr = xb + (size_t)(tn + n) * DIM + koff;
            #pragma unroll
            for (int kk = 0; kk < 4; ++kk) an[kk] = *(const bf16x8*)(xr + kk * 16);
        }

        // ---- layer 0: 32x64 slab, even/odd output columns ----
        f32x16 aE, aO;
        #pragma unroll
        for (int r = 0; r < 16; ++r) { aE[r] = 0.f; aO[r] = 0.f; }
        #pragma unroll
        for (int kk = 0; kk < 4; ++kk) {
            aE = __builtin_amdgcn_mfma_f32_32x32x16_bf16(a[kk], w0f[kk][0].v, aE, 0, 0, 0);
            aO = __builtin_amdgcn_mfma_f32_32x32x16_bf16(a[kk], w0f[kk][1].v, aO, 0, 0, 0);
        }
        // epilogue: bias + leaky + pack pair -> hs (wave-local, no barrier)
        #pragma unroll
        for (int r = 0; r < 16; ++r) {
            int m = (r & 3) + 8 * (r >> 2) + 4 * (lane >> 5);
            float vE = aE[r] + b0v.x; vE = vE > 0.f ? vE : NEG * vE;
            float vO = aO[r] + b0v.y; vO = vO > 0.f ? vO : NEG * vO;
            *(unsigned*)&h[m][2 * n] = pk_rne(vE, vO);
        }

        // ---- layer 1: A-frags from hs (row = n, same-wave data) ----
        f32x16 cE, cO;
        #pragma unroll
        for (int r = 0; r < 16; ++r) { cE[r] = 0.f; cO[r] = 0.f; }
        #pragma unroll
        for (int kk = 0; kk < 4; ++kk) {
            frag_u hf;
            hf.h[0] = *(const short4v*)&h[n][kk * 16 + koff];
            hf.h[1] = *(const short4v*)&h[n][kk * 16 + koff + 4];
            cE = __builtin_amdgcn_mfma_f32_32x32x16_bf16(hf.v, w1f[kk][0].v, cE, 0, 0, 0);
            cO = __builtin_amdgcn_mfma_f32_32x32x16_bf16(hf.v, w1f[kk][1].v, cO, 0, 0, 0);
        }

        // ---- deposit: lane n writes adjacent cols (2n,2n+1) of its group's
        //      64-col field into the f32 exchange slab (b64, 2-way max = free) ----
        #pragma unroll
        for (int r = 0; r < 16; ++r) {
            int m = (r & 3) + 8 * (r >> 2) + 4 * (lane >> 5);
            float2 o2;
            o2.x = cE[r] + b1v.x;
            o2.y = cO[r] + b1v.y;
            *(float2*)&sl[m][wave * DIM + 2 * n] = o2;
        }

        __syncthreads();

        // ---- cooperative store: 32 rows x 2 KB contiguous, dwordx4 bursts.
        //      wave instr = 1 KB contiguous; block covers rows tb..tb+31. ----
        {
            const int u     = tid & 127;    // 16B unit within the 2 KB row band
            const int rbase = tid >> 7;     // 0..3
            #pragma unroll
            for (int j = 0; j < 8; ++j) {
                int r = j * 4 + rbase;
                float4 v = *(const float4*)&sl[r][u * 4];
                *(float4*)(out + (size_t)(tb + r) * OUTSTRIDE
                               + (size_t)gs * (G_PER_BLK * DIM) + u * 4) = v;
            }
        }

        __syncthreads();                    // protect slab reuse next iter

        #pragma unroll
        for (int kk = 0; kk < 4; ++kk) a[kk] = an[kk];
    }
}

extern "C" void kernel_launch(void* const* d_in, const int* in_sizes, int n_in,
                              void* d_out, int out_size, void* d_ws, size_t ws_size,
                              hipStream_t stream) {
    const float* x  = (const float*)d_in[0];
    const float* W0 = (const float*)d_in[1];
    const float* b0 = (const float*)d_in[2];
    const float* W1 = (const float*)d_in[3];
    const float* b1 = (const float*)d_in[4];
    float* out = (float*)d_out;
    unsigned short* xb = (unsigned short*)d_ws;   // bf16 x, 128 KiB

    cvt_x_kernel<<<dim3(64), dim3(256), 0, stream>>>((const float4*)x, (uint2*)xb);
    convnn_kernel<<<dim3(512), dim3(512), 0, stream>>>(xb, W0, b0, W1, b1, out);
}

// Round 2
// 585.963 us; speedup vs baseline: 1.0509x; 1.0509x over previous
//
#include <hip/hip_runtime.h>

// ConvNN: out[b,g,j] = W1[g]·leaky(W0[g]·x[b] + b0[g]) + b1[g]
// B=1024, SIZE=2048, IN_DIM=D1=D2=64, neg_slope=0.2
//
// Round-4: identical structure to round-3 (8 waves x 8 groups per block,
// LDS exchange slab, 2 KB-contiguous cooperative stores) with ONE change:
// output stores are nontemporal (nt). Round-3 proved the store PATTERN is
// irrelevant (256B-scattered vs 2KB-contiguous = identical dur); theory is
// the cached-write PATH (L2 write-allocate/RFO + dirty eviction) caps
// effective write BW at ~2 TB/s while the harness's nt fill hits 6.26 TB/s.
// out is write-once/never-re-read -> nt bypasses allocation.
#define BATCH 1024
#define NGRP  2048
#define DIM   64
#define NEG   0.2f
#define OUTSTRIDE ((size_t)NGRP * DIM)   // 131072 floats between batch rows

#define G_PER_BLK 8
#define B_PER_BLK 512
#define ITERS     (B_PER_BLK / 32)       // 16

typedef __attribute__((ext_vector_type(8)))  short bf16x8;
typedef __attribute__((ext_vector_type(4)))  short short4v;
typedef __attribute__((ext_vector_type(16))) float f32x16;
typedef __attribute__((ext_vector_type(4)))  float f32x4;

union frag_u { bf16x8 v; unsigned u[4]; short4v h[2]; };

// pack two f32 -> two bf16 (RNE) in one u32 via v_perm
__device__ __forceinline__ unsigned pk_rne(float a, float b) {
    unsigned ua = __float_as_uint(a), ub = __float_as_uint(b);
    ua += 0x7fffu + ((ua >> 16) & 1u);
    ub += 0x7fffu + ((ub >> 16) & 1u);
    // result: low16 = bf16(a), high16 = bf16(b)
    return __builtin_amdgcn_perm(ub, ua, 0x07060302);
}

// ---- pre-kernel: x f32[1024][64] -> bf16[1024][64] in workspace ----
__global__ void cvt_x_kernel(const float4* __restrict__ x, uint2* __restrict__ xb) {
    int i = blockIdx.x * blockDim.x + threadIdx.x;   // 16384 threads, 1 float4 each
    float4 v = x[i];
    uint2 o;
    o.x = pk_rne(v.x, v.y);
    o.y = pk_rne(v.z, v.w);
    xb[i] = o;
}

__global__ __launch_bounds__(512, 2)
void convnn_kernel(const unsigned short* __restrict__ xb,  // bf16 [1024][64]
                   const float* __restrict__ W0, const float* __restrict__ b0,
                   const float* __restrict__ W1, const float* __restrict__ b1,
                   float* __restrict__ out) {
    // per-wave hidden slab: 32 rows x 64 cols bf16, +4 shorts pad (2-way max, free)
    __shared__ short hs[8][32][68];                  // 34,816 B
    // f32 output exchange slab: 32 batch rows x (8 groups x 64 cols)
    __shared__ float sl[32][G_PER_BLK * DIM];        // 65,536 B  (total ~98 KiB -> 1 blk/CU)

    const int bx   = blockIdx.x;
    const int gs   = bx & 255;              // group-set (8 groups)
    const int bh   = bx >> 8;               // batch half (0/1); bx and bx+256 share weights+XCD
    const int tid  = threadIdx.x;
    const int lane = tid & 63;
    const int wave = tid >> 6;              // 0..7
    const int n    = lane & 31;             // fragment row/col index
    const int koff = (lane >> 5) * 8;       // k sub-chunk per half-wave
    const int g    = gs * G_PER_BLK + wave; // this wave's group

    // ---- load weight B-fragments once (f32 global -> bf16 regs, RNE) ----
    // paired-column assignment: lane n covers weight rows 2n (even acc) and
    // 2n+1 (odd acc), so accE/accO hold adjacent output columns.
    frag_u w0f[4][2], w1f[4][2];
    {
        const float* w0p = W0 + (size_t)g * DIM * DIM;
        const float* w1p = W1 + (size_t)g * DIM * DIM;
        #pragma unroll
        for (int kk = 0; kk < 4; ++kk) {
            #pragma unroll
            for (int p = 0; p < 2; ++p) {
                const float* r0 = w0p + (size_t)(2 * n + p) * DIM + kk * 16 + koff;
                float4 lo = *(const float4*)r0;
                float4 hi = *(const float4*)(r0 + 4);
                w0f[kk][p].u[0] = pk_rne(lo.x, lo.y);
                w0f[kk][p].u[1] = pk_rne(lo.z, lo.w);
                w0f[kk][p].u[2] = pk_rne(hi.x, hi.y);
                w0f[kk][p].u[3] = pk_rne(hi.z, hi.w);
                const float* r1 = w1p + (size_t)(2 * n + p) * DIM + kk * 16 + koff;
                float4 lo1 = *(const float4*)r1;
                float4 hi1 = *(const float4*)(r1 + 4);
                w1f[kk][p].u[0] = pk_rne(lo1.x, lo1.y);
                w1f[kk][p].u[1] = pk_rne(lo1.z, lo1.w);
                w1f[kk][p].u[2] = pk_rne(hi1.x, hi1.y);
                w1f[kk][p].u[3] = pk_rne(hi1.z, hi1.w);
            }
        }
    }
    const float2 b0v = *(const float2*)(b0 + (size_t)g * DIM + 2 * n);
    const float2 b1v = *(const float2*)(b1 + (size_t)g * DIM + 2 * n);

    short (*h)[68] = hs[wave];
    const int tb0 = bh * B_PER_BLK;

    // prefetch tile 0 A-frags (bf16 direct from global, 16B each)
    bf16x8 a[4];
    {
        const unsigned short* xr = xb + (size_t)(tb0 + n) * DIM + koff;
        #pragma unroll
        for (int kk = 0; kk < 4; ++kk) a[kk] = *(const bf16x8*)(xr + kk * 16);
    }

    for (int i = 0; i < ITERS; ++i) {
        const int tb = tb0 + i * 32;        // this iter's 32 batch rows (all waves)
        // prefetch next tile
        bf16x8 an[4];
        {
            int tn = tb0 + (i < ITERS - 1 ? i + 1 : i) * 32;
            const unsigned short* xr = xb + (size_t)(tn + n) * DIM + koff;
            #pragma unroll
            for (int kk = 0; kk < 4; ++kk) an[kk] = *(const bf16x8*)(xr + kk * 16);
        }

        // ---- layer 0: 32x64 slab, even/odd output columns ----
        f32x16 aE, aO;
        #pragma unroll
        for (int r = 0; r < 16; ++r) { aE[r] = 0.f; aO[r] = 0.f; }
        #pragma unroll
        for (int kk = 0; kk < 4; ++kk) {
            aE = __builtin_amdgcn_mfma_f32_32x32x16_bf16(a[kk], w0f[kk][0].v, aE, 0, 0, 0);
            aO = __builtin_amdgcn_mfma_f32_32x32x16_bf16(a[kk], w0f[kk][1].v, aO, 0, 0, 0);
        }
        // epilogue: bias + leaky + pack pair -> hs (wave-local, no barrier)
        #pragma unroll
        for (int r = 0; r < 16; ++r) {
            int m = (r & 3) + 8 * (r >> 2) + 4 * (lane >> 5);
            float vE = aE[r] + b0v.x; vE = vE > 0.f ? vE : NEG * vE;
            float vO = aO[r] + b0v.y; vO = vO > 0.f ? vO : NEG * vO;
            *(unsigned*)&h[m][2 * n] = pk_rne(vE, vO);
        }

        // ---- layer 1: A-frags from hs (row = n, same-wave data) ----
        f32x16 cE, cO;
        #pragma unroll
        for (int r = 0; r < 16; ++r) { cE[r] = 0.f; cO[r] = 0.f; }
        #pragma unroll
        for (int kk = 0; kk < 4; ++kk) {
            frag_u hf;
            hf.h[0] = *(const short4v*)&h[n][kk * 16 + koff];
            hf.h[1] = *(const short4v*)&h[n][kk * 16 + koff + 4];
            cE = __builtin_amdgcn_mfma_f32_32x32x16_bf16(hf.v, w1f[kk][0].v, cE, 0, 0, 0);
            cO = __builtin_amdgcn_mfma_f32_32x32x16_bf16(hf.v, w1f[kk][1].v, cO, 0, 0, 0);
        }

        // ---- deposit: lane n writes adjacent cols (2n,2n+1) of its group's
        //      64-col field into the f32 exchange slab (b64, 2-way max = free) ----
        #pragma unroll
        for (int r = 0; r < 16; ++r) {
            int m = (r & 3) + 8 * (r >> 2) + 4 * (lane >> 5);
            float2 o2;
            o2.x = cE[r] + b1v.x;
            o2.y = cO[r] + b1v.y;
            *(float2*)&sl[m][wave * DIM + 2 * n] = o2;
        }

        __syncthreads();

        // ---- cooperative store: 32 rows x 2 KB contiguous, NONTEMPORAL
        //      dwordx4 bursts (nt: bypass L2 allocation/RFO; out is
        //      write-once, never re-read). ----
        {
            const int u     = tid & 127;    // 16B unit within the 2 KB row band
            const int rbase = tid >> 7;     // 0..3
            #pragma unroll
            for (int j = 0; j < 8; ++j) {
                int r = j * 4 + rbase;
                f32x4 v = *(const f32x4*)&sl[r][u * 4];
                __builtin_nontemporal_store(
                    v, (f32x4*)(out + (size_t)(tb + r) * OUTSTRIDE
                                    + (size_t)gs * (G_PER_BLK * DIM) + u * 4));
            }
        }

        __syncthreads();                    // protect slab reuse next iter

        #pragma unroll
        for (int kk = 0; kk < 4; ++kk) a[kk] = an[kk];
    }
}

extern "C" void kernel_launch(void* const* d_in, const int* in_sizes, int n_in,
                              void* d_out, int out_size, void* d_ws, size_t ws_size,
                              hipStream_t stream) {
    const float* x  = (const float*)d_in[0];
    const float* W0 = (const float*)d_in[1];
    const float* b0 = (const float*)d_in[2];
    const float* W1 = (const float*)d_in[3];
    const float* b1 = (const float*)d_in[4];
    float* out = (float*)d_out;
    unsigned short* xb = (unsigned short*)d_ws;   // bf16 x, 128 KiB

    cvt_x_kernel<<<dim3(64), dim3(256), 0, stream>>>((const float4*)x, (uint2*)xb);
    convnn_kernel<<<dim3(512), dim3(512), 0, stream>>>(xb, W0, b0, W1, b1, out);
}